// Round 10
// baseline (16.332 us; speedup 1.0000x reference)
//
#include <hip/hip_runtime.h>

// Problem constants (from reference)
#define BATCH     4096
#define N_CTX     8
#define N_TGT     16
#define NUM_DOCS  500
#define NUM_WORDS 8000
#define VEC_DIM   128
#define N_TILES   ((NUM_WORDS / 32) * (VEC_DIM / 32))  // 1000

// Native clang vector types.
typedef float          floatx4  __attribute__((ext_vector_type(4)));
typedef unsigned short ushortx8 __attribute__((ext_vector_type(8)));

__device__ __forceinline__ unsigned short f2bf(float f) {
  union { float f; unsigned int i; } v;
  v.f = f;
  const unsigned int r = v.i + 0x7FFFu + ((v.i >> 16) & 1u);  // RNE
  return (unsigned short)(r >> 16);
}
__device__ __forceinline__ float bf2f(unsigned short u) {
  union { unsigned int i; float f; } v;
  v.i = ((unsigned int)u) << 16;
  return v.f;
}

// ---------------------------------------------------------------------------
// K1: D/W gather-sum -> X (fp32)  ∥  transpose O -> OTb (bf16 rows).
// D/W gathers (longest HBM latency) issued first; O-tile loads + LDS
// transpose run under that latency. Known-good from R9.
// ---------------------------------------------------------------------------
__global__ __launch_bounds__(256, 2) void k1_gather_transpose(
    const int* __restrict__ ctx, const int* __restrict__ docs,
    const float* __restrict__ D, const float* __restrict__ W,
    const float* __restrict__ O, unsigned short* __restrict__ OTb,
    float* __restrict__ X) {
  const int tid  = threadIdx.x;
  const int wave = tid >> 6;
  const int lane = tid & 63;
  const int hl   = lane & 31;
  const int b = (blockIdx.x * 4 + wave) * 2 + (lane >> 5);  // 8 batches/block

  __shared__ float tile[2][32][33];  // +1 pad: conflict-free
  const int tx = tid & 31;
  const int ty = tid >> 5;  // 0..7

  // ---- phase A: issue D/W gather loads (longest latency first) ----
  const int4 c0 = *(const int4*)(ctx + b * N_CTX);
  const int4 c1 = *(const int4*)(ctx + b * N_CTX + 4);
  const int  doc = docs[b];
  const int cw[N_CTX] = {c0.x, c0.y, c0.z, c0.w, c1.x, c1.y, c1.z, c1.w};
  const float* Dbase = D + (size_t)doc * (NUM_WORDS * VEC_DIM) + 4 * hl;
  const float* Wbase = W + 4 * hl;
  floatx4 dd[N_CTX], ww[N_CTX];
#pragma unroll
  for (int c = 0; c < N_CTX; ++c) {
    // D has zero reuse (2 GB): stream past L2.
    dd[c] = __builtin_nontemporal_load(
        (const floatx4*)(Dbase + (size_t)cw[c] * VEC_DIM));
    ww[c] = *(const floatx4*)(Wbase + (size_t)cw[c] * VEC_DIM);
  }

  // ---- phase B: O-tile loads ----
  float r[2][4];
  int wB[2], vB[2], tok[2];
#pragma unroll
  for (int s = 0; s < 2; ++s) {
    const int ti = blockIdx.x * 2 + s;  // 0..1023; 1000 real tiles
    tok[s] = (ti < N_TILES);
    wB[s] = (ti % (NUM_WORDS / 32)) * 32;
    vB[s] = (ti / (NUM_WORDS / 32)) * 32;
    if (tok[s]) {
#pragma unroll
      for (int i = 0; i < 4; ++i)
        r[s][i] = O[(size_t)(vB[s] + ty + 8 * i) * NUM_WORDS + (wB[s] + tx)];
    }
  }

  // ---- phase C: LDS transpose -> OTb (bf16), overlaps gather latency ----
#pragma unroll
  for (int s = 0; s < 2; ++s) {
    if (tok[s]) {
#pragma unroll
      for (int i = 0; i < 4; ++i) tile[s][ty + 8 * i][tx] = r[s][i];
    }
  }
  __syncthreads();
#pragma unroll
  for (int s = 0; s < 2; ++s) {
    if (tok[s]) {
#pragma unroll
      for (int i = 0; i < 4; ++i)
        OTb[(size_t)(wB[s] + ty + 8 * i) * VEC_DIM + (vB[s] + tx)] =
            f2bf(tile[s][tx][ty + 8 * i]);
    }
  }

  // ---- phase D: accumulate and store X ----
  floatx4 acc = {0.f, 0.f, 0.f, 0.f};
#pragma unroll
  for (int c = 0; c < N_CTX; ++c) acc += dd[c] + ww[c];
  *(floatx4*)(X + (size_t)b * VEC_DIM + 4 * hl) = acc;
}

// ---------------------------------------------------------------------------
// K2: dot phase, 8-comp slicing. Half-wave = 1 batch. Lane hl: i=hl&15 owns
// comps [8i,8i+8), g=hl>>4 owns odd/even targets. Each ushortx8 load fetches
// TWO random OT rows (lanes 0-15 -> row 2j, lanes 16-31 -> row 2j+1):
// 8 O-load instructions for 16 rows. Reduction: fold j-bits onto lane-bits
// 3/2/1 (7 shuffles) + final xor1 = 8 shuffles for 16 sums.
// ---------------------------------------------------------------------------
__global__ __launch_bounds__(256, 2) void k2_dot(
    const int* __restrict__ tgt, const float* __restrict__ X,
    const unsigned short* __restrict__ OTb, float* __restrict__ out) {
  const int wave = threadIdx.x >> 6;
  const int lane = threadIdx.x & 63;
  const int hl   = lane & 31;
  const int i    = hl & 15;
  const int g    = hl >> 4;  // 0: even targets, 1: odd targets
  const int b = (blockIdx.x * 4 + wave) * 2 + (lane >> 5);

  const int4 t0 = *(const int4*)(tgt + b * N_TGT);
  const int4 t1 = *(const int4*)(tgt + b * N_TGT + 4);
  const int4 t2 = *(const int4*)(tgt + b * N_TGT + 8);
  const int4 t3 = *(const int4*)(tgt + b * N_TGT + 12);
  const int tw[N_TGT] = {t0.x, t0.y, t0.z, t0.w, t1.x, t1.y, t1.z, t1.w,
                         t2.x, t2.y, t2.z, t2.w, t3.x, t3.y, t3.z, t3.w};

  // ---- 8 O-load instructions: pair (2j, 2j+1) per instruction ----
  const unsigned short* Obase = OTb + 8 * i;
  ushortx8 o[8];
#pragma unroll
  for (int j = 0; j < 8; ++j) {
    const int tA = tw[2 * j];      // constant indices -> registers;
    const int tB = tw[2 * j + 1];  // 2-way select on g -> v_cndmask
    const int row = g ? tB : tA;
    o[j] = *(const ushortx8*)(Obase + (size_t)row * VEC_DIM);
  }

  // ---- X slice: comps [8i, 8i+8) ----
  const float* Xb = X + (size_t)b * VEC_DIM + 8 * i;
  const floatx4 xa = *(const floatx4*)(Xb);
  const floatx4 xb = *(const floatx4*)(Xb + 4);

  float p[8];
#pragma unroll
  for (int j = 0; j < 8; ++j) {
    p[j] = xa.x * bf2f(o[j][0]) + xa.y * bf2f(o[j][1]) +
           xa.z * bf2f(o[j][2]) + xa.w * bf2f(o[j][3]) +
           xb.x * bf2f(o[j][4]) + xb.y * bf2f(o[j][5]) +
           xb.z * bf2f(o[j][6]) + xb.w * bf2f(o[j][7]);
  }

  // ---- fold j-bit2 := lane-bit3 (4 shuffles) ----
  const bool hA = (hl & 8) != 0;
  float q[4];
#pragma unroll
  for (int m = 0; m < 4; ++m) {
    const float send = hA ? p[m] : p[m + 4];
    const float recv = __shfl_xor(send, 8, 64);
    q[m] = (hA ? p[m + 4] : p[m]) + recv;
  }
  // ---- fold j-bit1 := lane-bit2 (2 shuffles) ----
  const bool hB = (hl & 4) != 0;
  float r[2];
#pragma unroll
  for (int m = 0; m < 2; ++m) {
    const float send = hB ? q[m] : q[m + 2];
    const float recv = __shfl_xor(send, 4, 64);
    r[m] = (hB ? q[m + 2] : q[m]) + recv;
  }
  // ---- fold j-bit0 := lane-bit1 (1 shuffle) ----
  const bool hC = (hl & 2) != 0;
  float s;
  {
    const float send = hC ? r[0] : r[1];
    const float recv = __shfl_xor(send, 2, 64);
    s = (hC ? r[1] : r[0]) + recv;
  }
  // ---- final: sum over lane-bit0 ----
  s += __shfl_xor(s, 1, 64);

  // Lane hl (even) holds S[t], j=(hl>>1)&7, t=2j+g: 16 distinct targets/batch.
  if ((hl & 1) == 0) out[b * N_TGT + 2 * ((hl >> 1) & 7) + g] = s;
}

extern "C" void kernel_launch(void* const* d_in, const int* in_sizes, int n_in,
                              void* d_out, int out_size, void* d_ws, size_t ws_size,
                              hipStream_t stream) {
  const int*   ctx  = (const int*)d_in[0];    // (4096, 8)
  const int*   docs = (const int*)d_in[1];    // (4096,)
  const int*   tgt  = (const int*)d_in[2];    // (4096, 16)
  const float* D    = (const float*)d_in[3];  // (500, 8000, 128)
  const float* W    = (const float*)d_in[4];  // (8000, 128)
  const float* O    = (const float*)d_in[5];  // (128, 8000)
  float*       out  = (float*)d_out;          // (4096, 16)

  unsigned short* OTb = (unsigned short*)d_ws;                  // 2 MB (bf16)
  float* X = (float*)((char*)d_ws + (size_t)NUM_WORDS * VEC_DIM * 2);  // 2 MB

  k1_gather_transpose<<<dim3(BATCH / 8), dim3(256), 0, stream>>>(
      ctx, docs, D, W, O, OTb, X);
  k2_dot<<<dim3(BATCH / 8), dim3(256), 0, stream>>>(tgt, X, OTb, out);
}